// Round 1
// baseline (202.353 us; speedup 1.0000x reference)
//
#include <hip/hip_runtime.h>
#include <hip/hip_bf16.h>
#include <math.h>

// Problem constants
#define BB 32
#define TT 4096
#define CC 64
#define DD 512
#define NW 31          // number of windows
#define WIN 256
#define HOP 128
#define NROWS (BB * NW)   // 992

// ---------------------------------------------------------------------------
// Kernel 1: band power via direct 50-bin DFT.
// One block per (b, n) window. 256 threads: c = tid&63 (channel), g = tid>>6
// (wave id). Wave g handles freqs f = 1+g, 5+g, ... (<=50) -> <=13 freqs.
// Window staged in LDS in two 128-row halves (32 KB each) to stay <64KB.
// cos/sin table (256 entries) in LDS; table reads are wave-uniform broadcasts.
// ---------------------------------------------------------------------------
__global__ __launch_bounds__(256) void k_bandpower(const float* __restrict__ x,
                                                   float* __restrict__ feat) {
    __shared__ float  xs[128 * 64];      // 32 KB: half-window, [t][c]
    __shared__ float2 tab[256];          // 2 KB: (cos, sin)(2*pi*a/256)
    __shared__ float  bpart[4][5][64];   // 5 KB: per-wave partial band sums

    const int tid = threadIdx.x;
    const int c   = tid & 63;
    const int g   = tid >> 6;            // wave id 0..3
    const int blk = blockIdx.x;          // 0..991
    const int b   = blk / NW;
    const int n   = blk % NW;

    // fill cos/sin table
    {
        float ang = (float)tid * (2.0f * 3.14159265358979323846f / 256.0f);
        float s, cs;
        sincosf(ang, &s, &cs);
        tab[tid] = make_float2(cs, s);
    }
    // zero band partials
    for (int i = tid; i < 4 * 5 * 64; i += 256) ((float*)bpart)[i] = 0.0f;

    float re[13], im[13];
#pragma unroll
    for (int j = 0; j < 13; ++j) { re[j] = 0.0f; im[j] = 0.0f; }

    const size_t winBase = ((size_t)b * TT + (size_t)n * HOP) * CC;

    for (int half = 0; half < 2; ++half) {
        // stage 128 rows x 64 channels (contiguous 8192 floats) into LDS
        const float4* src = (const float4*)(x + winBase + (size_t)half * 128 * CC);
        float4* dst = (float4*)xs;
        for (int i = tid; i < (128 * 64) / 4; i += 256) dst[i] = src[i];
        __syncthreads();

        for (int tt = 0; tt < 128; tt += 8) {
            float xv[8];
#pragma unroll
            for (int i = 0; i < 8; ++i) xv[i] = xs[(tt + i) * 64 + c];
            const int tg = half * 128 + tt;
#pragma unroll
            for (int j = 0; j < 13; ++j) {
                const int f = 1 + g + 4 * j;   // may exceed 50 for g>=2; harmless
#pragma unroll
                for (int i = 0; i < 8; ++i) {
                    const int a = (f * (tg + i)) & 255;
                    const float2 cs = tab[a];
                    re[j] = fmaf(xv[i], cs.x, re[j]);
                    im[j] = fmaf(xv[i], cs.y, im[j]);
                }
            }
        }
        __syncthreads();   // protect xs before next half overwrites it
    }

    // accumulate band partial sums (thread exclusively owns bpart[g][*][c])
#pragma unroll
    for (int j = 0; j < 13; ++j) {
        const int f = 1 + g + 4 * j;
        if (f > 50) continue;
        const float p = re[j] * re[j] + im[j] * im[j];
        if (f <= 4)            bpart[g][0][c] += p;
        if (f >= 4 && f <= 8)  bpart[g][1][c] += p;
        if (f >= 8 && f <= 13) bpart[g][2][c] += p;
        if (f >= 13 && f <= 30) bpart[g][3][c] += p;
        if (f >= 30)           bpart[g][4][c] += p;
    }
    __syncthreads();

    // reduce over waves, apply 1/count weights, write feat row (320)
    const float wband[5] = {1.0f / 4.0f, 1.0f / 5.0f, 1.0f / 6.0f,
                            1.0f / 18.0f, 1.0f / 21.0f};
    for (int idx = tid; idx < 320; idx += 256) {
        const int k  = idx >> 6;
        const int cc = idx & 63;
        float s = bpart[0][k][cc] + bpart[1][k][cc] +
                  bpart[2][k][cc] + bpart[3][k][cc];
        feat[(size_t)blk * 320 + idx] = s * wband[k];
    }
}

// ---------------------------------------------------------------------------
// Kernel 2: MLP. 4 rows per block, 256 threads.
// h = relu(feat @ W1 + b1); feat2 = h @ W2 + b2.
// W1: (320,256) row-major, W2: (256,512) row-major.
// ---------------------------------------------------------------------------
__global__ __launch_bounds__(256) void k_mlp(const float* __restrict__ feat,
                                             const float* __restrict__ W1,
                                             const float* __restrict__ b1,
                                             const float* __restrict__ W2,
                                             const float* __restrict__ b2,
                                             float* __restrict__ feat2) {
    __shared__ float fs[4][320];
    __shared__ float hs[4][256];

    const int tid  = threadIdx.x;
    const int row0 = blockIdx.x * 4;

    for (int i = tid; i < 4 * 320; i += 256)
        ((float*)fs)[i] = feat[(size_t)row0 * 320 + i];
    __syncthreads();

    // phase 1: hidden (256 wide), thread owns column tid
    float acc[4];
    {
        const float bias = b1[tid];
#pragma unroll
        for (int r = 0; r < 4; ++r) acc[r] = bias;
        for (int i = 0; i < 320; ++i) {
            const float w = W1[(size_t)i * 256 + tid];
#pragma unroll
            for (int r = 0; r < 4; ++r) acc[r] = fmaf(fs[r][i], w, acc[r]);
        }
#pragma unroll
        for (int r = 0; r < 4; ++r) hs[r][tid] = fmaxf(acc[r], 0.0f);
    }
    __syncthreads();

    // phase 2: output (512 wide), thread owns columns tid and tid+256
    float o0[4], o1[4];
    {
        const float bias0 = b2[tid];
        const float bias1 = b2[tid + 256];
#pragma unroll
        for (int r = 0; r < 4; ++r) { o0[r] = bias0; o1[r] = bias1; }
        for (int i = 0; i < 256; ++i) {
            const float w0 = W2[(size_t)i * 512 + tid];
            const float w1 = W2[(size_t)i * 512 + tid + 256];
#pragma unroll
            for (int r = 0; r < 4; ++r) {
                const float h = hs[r][i];
                o0[r] = fmaf(h, w0, o0[r]);
                o1[r] = fmaf(h, w1, o1[r]);
            }
        }
    }
#pragma unroll
    for (int r = 0; r < 4; ++r) {
        feat2[(size_t)(row0 + r) * 512 + tid]       = o0[r];
        feat2[(size_t)(row0 + r) * 512 + tid + 256] = o1[r];
    }
}

// ---------------------------------------------------------------------------
// Kernel 3: linear interpolation nW=31 -> T=4096 (align_corners=False).
// Block handles 2 consecutive t of one b; 256 threads; float4 I/O.
// ---------------------------------------------------------------------------
__global__ __launch_bounds__(256) void k_interp(const float* __restrict__ feat2,
                                                float* __restrict__ out) {
    const int tid  = threadIdx.x;
    const int bt   = blockIdx.x * 2 + (tid >> 7);  // global (b*T + t)
    const int d4   = tid & 127;                    // float4 index within row
    const int t    = bt & (TT - 1);
    const int b    = bt >> 12;

    float pos = ((float)t + 0.5f) * (31.0f / 4096.0f) - 0.5f;
    pos = fminf(fmaxf(pos, 0.0f), 30.0f);
    const int   i0 = (int)pos;            // pos >= 0, trunc == floor
    const int   i1 = min(i0 + 1, 30);
    const float w  = pos - (float)i0;
    const float w0 = 1.0f - w;

    const float4* r0 = (const float4*)(feat2 + ((size_t)b * NW + i0) * DD);
    const float4* r1 = (const float4*)(feat2 + ((size_t)b * NW + i1) * DD);
    float4* o = (float4*)(out + (size_t)bt * DD);

    const float4 a = r0[d4];
    const float4 c = r1[d4];
    float4 res;
    res.x = a.x * w0 + c.x * w;
    res.y = a.y * w0 + c.y * w;
    res.z = a.z * w0 + c.z * w;
    res.w = a.w * w0 + c.w * w;
    o[d4] = res;
}

// ---------------------------------------------------------------------------
extern "C" void kernel_launch(void* const* d_in, const int* in_sizes, int n_in,
                              void* d_out, int out_size, void* d_ws, size_t ws_size,
                              hipStream_t stream) {
    const float* x  = (const float*)d_in[0];
    const float* W1 = (const float*)d_in[1];
    const float* b1 = (const float*)d_in[2];
    const float* W2 = (const float*)d_in[3];
    const float* b2 = (const float*)d_in[4];
    float* out = (float*)d_out;

    float* feat  = (float*)d_ws;                 // NROWS*320 floats = 1.27 MB
    float* feat2 = feat + (size_t)NROWS * 320;   // NROWS*512 floats = 2.03 MB

    k_bandpower<<<NROWS, 256, 0, stream>>>(x, feat);
    k_mlp<<<NROWS / 4, 256, 0, stream>>>(feat, W1, b1, W2, b2, feat2);
    k_interp<<<(BB * TT) / 2, 256, 0, stream>>>(feat2, out);
}

// Round 3
// 116.375 us; speedup vs baseline: 1.7388x; 1.7388x over previous
//
#include <hip/hip_runtime.h>
#include <hip/hip_bf16.h>
#include <math.h>

// Problem constants
#define BB 32
#define TT 4096
#define CC 64
#define DD 512
#define NW 31          // number of windows
#define WIN 256
#define HOP 128
#define NROWS (BB * NW)   // 992

typedef float f32x4 __attribute__((ext_vector_type(4)));

// ---------------------------------------------------------------------------
// Kernel 1: band power via Goertzel (no twiddle table -> no LDS-pipe bound).
// One block per (b, n) window. 256 threads: c = tid&63 (channel), g = tid>>6
// (wave id). Wave g handles freqs f = 1+g+4j, j=0..12 (f>50 discarded).
// Recurrence: s_t = x_t + coef*s1 - s2, coef = 2*cos(2*pi*f/256).
// Power: |X_f|^2 = s1^2 + s2^2 - coef*s1*s2 (phase-free, exact identity).
// Window staged in LDS in two 128-row halves (32 KB each).
// ---------------------------------------------------------------------------
__global__ __launch_bounds__(256) void k_bandpower(const float* __restrict__ x,
                                                   float* __restrict__ feat) {
    __shared__ float xs[128 * 64];       // 32 KB: half-window, [t][c]
    __shared__ float bpart[4][5][64];    // 5 KB: per-wave partial band sums

    const int tid = threadIdx.x;
    const int c   = tid & 63;
    const int g   = tid >> 6;            // wave id 0..3
    const int blk = blockIdx.x;          // 0..991
    const int b   = blk / NW;
    const int n   = blk % NW;

    // zero band partials
    for (int i = tid; i < 4 * 5 * 64; i += 256) ((float*)bpart)[i] = 0.0f;

    // per-thread Goertzel state: 13 chains
    float coef[13], s1[13], s2[13];
#pragma unroll
    for (int j = 0; j < 13; ++j) {
        const int f = 1 + g + 4 * j;
        coef[j] = 2.0f * cospif((float)f * (1.0f / 128.0f));  // 2cos(2*pi*f/256)
        s1[j] = 0.0f;
        s2[j] = 0.0f;
    }

    const size_t winBase = ((size_t)b * TT + (size_t)n * HOP) * CC;

    for (int half = 0; half < 2; ++half) {
        // stage 128 rows x 64 channels (contiguous 8192 floats) into LDS
        const f32x4* src = (const f32x4*)(x + winBase + (size_t)half * 128 * CC);
        f32x4* dst = (f32x4*)xs;
        for (int i = tid; i < (128 * 64) / 4; i += 256) dst[i] = src[i];
        __syncthreads();

#pragma unroll 4
        for (int tt = 0; tt < 128; ++tt) {
            const float xv = xs[tt * 64 + c];
#pragma unroll
            for (int j = 0; j < 13; ++j) {
                const float sn = fmaf(coef[j], s1[j], xv - s2[j]);
                s2[j] = s1[j];
                s1[j] = sn;
            }
        }
        __syncthreads();   // protect xs before next half overwrites it
    }

    // accumulate band partial sums (thread exclusively owns bpart[g][*][c])
#pragma unroll
    for (int j = 0; j < 13; ++j) {
        const int f = 1 + g + 4 * j;
        if (f > 50) continue;
        const float p = fmaf(s1[j], s1[j],
                        fmaf(s2[j], s2[j], -coef[j] * s1[j] * s2[j]));
        if (f <= 4)             bpart[g][0][c] += p;
        if (f >= 4 && f <= 8)   bpart[g][1][c] += p;
        if (f >= 8 && f <= 13)  bpart[g][2][c] += p;
        if (f >= 13 && f <= 30) bpart[g][3][c] += p;
        if (f >= 30)            bpart[g][4][c] += p;
    }
    __syncthreads();

    // reduce over waves, apply 1/count weights, write feat row (320)
    const float wband[5] = {1.0f / 4.0f, 1.0f / 5.0f, 1.0f / 6.0f,
                            1.0f / 18.0f, 1.0f / 21.0f};
    for (int idx = tid; idx < 320; idx += 256) {
        const int k  = idx >> 6;
        const int cc = idx & 63;
        float s = bpart[0][k][cc] + bpart[1][k][cc] +
                  bpart[2][k][cc] + bpart[3][k][cc];
        feat[(size_t)blk * 320 + idx] = s * wband[k];
    }
}

// ---------------------------------------------------------------------------
// Kernel 2: MLP. 4 rows per block, 256 threads.
// h = relu(feat @ W1 + b1); feat2 = h @ W2 + b2.
// W1: (320,256) row-major, W2: (256,512) row-major.
// ---------------------------------------------------------------------------
__global__ __launch_bounds__(256) void k_mlp(const float* __restrict__ feat,
                                             const float* __restrict__ W1,
                                             const float* __restrict__ b1,
                                             const float* __restrict__ W2,
                                             const float* __restrict__ b2,
                                             float* __restrict__ feat2) {
    __shared__ float fs[4][320];
    __shared__ float hs[4][256];

    const int tid  = threadIdx.x;
    const int row0 = blockIdx.x * 4;

    for (int i = tid; i < 4 * 320; i += 256)
        ((float*)fs)[i] = feat[(size_t)row0 * 320 + i];
    __syncthreads();

    // phase 1: hidden (256 wide), thread owns column tid
    float acc[4];
    {
        const float bias = b1[tid];
#pragma unroll
        for (int r = 0; r < 4; ++r) acc[r] = bias;
        for (int i = 0; i < 320; ++i) {
            const float w = W1[(size_t)i * 256 + tid];
#pragma unroll
            for (int r = 0; r < 4; ++r) acc[r] = fmaf(fs[r][i], w, acc[r]);
        }
#pragma unroll
        for (int r = 0; r < 4; ++r) hs[r][tid] = fmaxf(acc[r], 0.0f);
    }
    __syncthreads();

    // phase 2: output (512 wide), thread owns columns tid and tid+256
    float o0[4], o1[4];
    {
        const float bias0 = b2[tid];
        const float bias1 = b2[tid + 256];
#pragma unroll
        for (int r = 0; r < 4; ++r) { o0[r] = bias0; o1[r] = bias1; }
        for (int i = 0; i < 256; ++i) {
            const float w0 = W2[(size_t)i * 512 + tid];
            const float w1 = W2[(size_t)i * 512 + tid + 256];
#pragma unroll
            for (int r = 0; r < 4; ++r) {
                const float h = hs[r][i];
                o0[r] = fmaf(h, w0, o0[r]);
                o1[r] = fmaf(h, w1, o1[r]);
            }
        }
    }
#pragma unroll
    for (int r = 0; r < 4; ++r) {
        feat2[(size_t)(row0 + r) * 512 + tid]       = o0[r];
        feat2[(size_t)(row0 + r) * 512 + tid + 256] = o1[r];
    }
}

// ---------------------------------------------------------------------------
// Kernel 3: linear interpolation nW=31 -> T=4096 (align_corners=False).
// Block handles 2 consecutive t of one b; 256 threads; float4 I/O.
// Output is never re-read -> nontemporal stores (native vector type).
// ---------------------------------------------------------------------------
__global__ __launch_bounds__(256) void k_interp(const float* __restrict__ feat2,
                                                float* __restrict__ out) {
    const int tid  = threadIdx.x;
    const int bt   = blockIdx.x * 2 + (tid >> 7);  // global (b*T + t)
    const int d4   = tid & 127;                    // float4 index within row
    const int t    = bt & (TT - 1);
    const int b    = bt >> 12;

    float pos = ((float)t + 0.5f) * (31.0f / 4096.0f) - 0.5f;
    pos = fminf(fmaxf(pos, 0.0f), 30.0f);
    const int   i0 = (int)pos;            // pos >= 0, trunc == floor
    const int   i1 = min(i0 + 1, 30);
    const float w  = pos - (float)i0;
    const float w0 = 1.0f - w;

    const f32x4* r0 = (const f32x4*)(feat2 + ((size_t)b * NW + i0) * DD);
    const f32x4* r1 = (const f32x4*)(feat2 + ((size_t)b * NW + i1) * DD);
    f32x4* o = (f32x4*)(out + (size_t)bt * DD);

    const f32x4 a  = r0[d4];
    const f32x4 cc = r1[d4];
    f32x4 res = a * w0 + cc * w;
    __builtin_nontemporal_store(res, &o[d4]);
}

// ---------------------------------------------------------------------------
extern "C" void kernel_launch(void* const* d_in, const int* in_sizes, int n_in,
                              void* d_out, int out_size, void* d_ws, size_t ws_size,
                              hipStream_t stream) {
    const float* x  = (const float*)d_in[0];
    const float* W1 = (const float*)d_in[1];
    const float* b1 = (const float*)d_in[2];
    const float* W2 = (const float*)d_in[3];
    const float* b2 = (const float*)d_in[4];
    float* out = (float*)d_out;

    float* feat  = (float*)d_ws;                 // NROWS*320 floats = 1.27 MB
    float* feat2 = feat + (size_t)NROWS * 320;   // NROWS*512 floats = 2.03 MB

    k_bandpower<<<NROWS, 256, 0, stream>>>(x, feat);
    k_mlp<<<NROWS / 4, 256, 0, stream>>>(feat, W1, b1, W2, b2, feat2);
    k_interp<<<(BB * TT) / 2, 256, 0, stream>>>(feat2, out);
}

// Round 4
// 111.591 us; speedup vs baseline: 1.8133x; 1.0429x over previous
//
#include <hip/hip_runtime.h>
#include <hip/hip_bf16.h>
#include <math.h>

// Problem constants
#define BB 32
#define TT 4096
#define CC 64
#define DD 512
#define NW 31          // number of windows
#define WIN 256
#define HOP 128
#define NROWS (BB * NW)   // 992

typedef float f32x4 __attribute__((ext_vector_type(4)));

// ---------------------------------------------------------------------------
// Kernel 1: band power via folded Goertzel.
// Fold: e^{-2pi i f (t+128)/256} = (-1)^f e^{-2pi i f t/256}, so
//   even f: X_f = sum_{t<128} u_t w^{ft},  u_t = x_t + x_{t+128}
//   odd  f: X_f = sum_{t<128} v_t w^{ft},  v_t = x_t - x_{t+128}
// -> every chain runs 128 steps instead of 256 (2x VALU reduction).
// One block per (b,n) window; 512 threads = 8 waves; c = tid&63, g = tid>>6.
// Wave g owns freqs f = 1+g+8j, j=0..6 (f>50 discarded; parity(f) uniform
// per wave -> u/v select is wave-uniform).
// Goertzel: s_t = y_t + coef*s1 - s2, coef = 2cos(2pi f/256);
// |X|^2 = s1^2 + s2^2 - coef*s1*s2 (N-independent identity).
// LDS: u[128][64] | v[128][64] = 64 KB, re-aliased as bpart[8][5][64] after
// the compute barrier.
// ---------------------------------------------------------------------------
__global__ __launch_bounds__(512) void k_bandpower(const float* __restrict__ x,
                                                   float* __restrict__ feat) {
    __shared__ float lds[16384];         // 64 KB
    float* u = lds;                      // [128][64]
    float* v = lds + 8192;               // [128][64]

    const int tid = threadIdx.x;
    const int c   = tid & 63;
    const int g   = tid >> 6;            // wave id 0..7
    const int blk = blockIdx.x;          // 0..991
    const int b   = blk / NW;
    const int n   = blk % NW;

    // staged fold: read both halves once, write u,v (coalesced f32x4)
    const size_t winBase = ((size_t)b * TT + (size_t)n * HOP) * CC;
    const f32x4* h0 = (const f32x4*)(x + winBase);              // t = 0..127
    const f32x4* h1 = (const f32x4*)(x + winBase + 128 * CC);   // t = 128..255
    f32x4* u4 = (f32x4*)u;
    f32x4* v4 = (f32x4*)v;
    for (int i = tid; i < 2048; i += 512) {
        const f32x4 a  = h0[i];
        const f32x4 bb = h1[i];
        u4[i] = a + bb;
        v4[i] = a - bb;
    }
    __syncthreads();

    // 7 Goertzel chains per thread, 128 steps, on u (even f) or v (odd f)
    float coef[7], s1[7], s2[7];
#pragma unroll
    for (int j = 0; j < 7; ++j) {
        const int f = 1 + g + 8 * j;
        coef[j] = 2.0f * cospif((float)f * (1.0f / 128.0f)); // 2cos(2pi f/256)
        s1[j] = 0.0f;
        s2[j] = 0.0f;
    }
    // parity(f) = parity(1+g): g odd -> f even -> u; g even -> f odd -> v
    const float* src = ((g & 1) ? u : v) + c;

#pragma unroll 4
    for (int tt = 0; tt < 128; ++tt) {
        const float xv = src[tt * 64];
#pragma unroll
        for (int j = 0; j < 7; ++j) {
            const float sn = fmaf(coef[j], s1[j], xv - s2[j]);
            s2[j] = s1[j];
            s1[j] = sn;
        }
    }
    __syncthreads();   // done reading u/v; lds is re-aliased below

    // per-thread band sums
    float pb[5] = {0.0f, 0.0f, 0.0f, 0.0f, 0.0f};
#pragma unroll
    for (int j = 0; j < 7; ++j) {
        const int f = 1 + g + 8 * j;
        if (f > 50) continue;            // wave-uniform guard
        const float p = fmaf(s1[j], s1[j],
                        fmaf(s2[j], s2[j], -coef[j] * s1[j] * s2[j]));
        if (f <= 4)             pb[0] += p;
        if (f >= 4 && f <= 8)   pb[1] += p;
        if (f >= 8 && f <= 13)  pb[2] += p;
        if (f >= 13 && f <= 30) pb[3] += p;
        if (f >= 30)            pb[4] += p;
    }

    // cross-wave reduction via re-aliased LDS (each (g,k,c) written once)
    float (*bpart)[5][64] = (float (*)[5][64])lds;
#pragma unroll
    for (int k = 0; k < 5; ++k) bpart[g][k][c] = pb[k];
    __syncthreads();

    const float wband[5] = {1.0f / 4.0f, 1.0f / 5.0f, 1.0f / 6.0f,
                            1.0f / 18.0f, 1.0f / 21.0f};
    for (int idx = tid; idx < 320; idx += 512) {
        const int k  = idx >> 6;
        const int cc = idx & 63;
        float s = 0.0f;
#pragma unroll
        for (int gg = 0; gg < 8; ++gg) s += bpart[gg][k][cc];
        feat[(size_t)blk * 320 + idx] = s * wband[k];
    }
}

// ---------------------------------------------------------------------------
// Kernel 2: MLP. 8 rows per block, 256 threads.
// h = relu(feat @ W1 + b1); feat2 = h @ W2 + b2.
// W1: (320,256) row-major, W2: (256,512) row-major.
// ---------------------------------------------------------------------------
__global__ __launch_bounds__(256) void k_mlp(const float* __restrict__ feat,
                                             const float* __restrict__ W1,
                                             const float* __restrict__ b1,
                                             const float* __restrict__ W2,
                                             const float* __restrict__ b2,
                                             float* __restrict__ feat2) {
    __shared__ float fs[8][320];
    __shared__ float hs[8][256];

    const int tid  = threadIdx.x;
    const int row0 = blockIdx.x * 8;

    for (int i = tid; i < 8 * 320; i += 256)
        ((float*)fs)[i] = feat[(size_t)row0 * 320 + i];
    __syncthreads();

    // phase 1: hidden (256 wide), thread owns column tid
    float acc[8];
    {
        const float bias = b1[tid];
#pragma unroll
        for (int r = 0; r < 8; ++r) acc[r] = bias;
        for (int i = 0; i < 320; ++i) {
            const float w = W1[(size_t)i * 256 + tid];
#pragma unroll
            for (int r = 0; r < 8; ++r) acc[r] = fmaf(fs[r][i], w, acc[r]);
        }
#pragma unroll
        for (int r = 0; r < 8; ++r) hs[r][tid] = fmaxf(acc[r], 0.0f);
    }
    __syncthreads();

    // phase 2: output (512 wide), thread owns columns tid and tid+256
    float o0[8], o1[8];
    {
        const float bias0 = b2[tid];
        const float bias1 = b2[tid + 256];
#pragma unroll
        for (int r = 0; r < 8; ++r) { o0[r] = bias0; o1[r] = bias1; }
        for (int i = 0; i < 256; ++i) {
            const float w0 = W2[(size_t)i * 512 + tid];
            const float w1 = W2[(size_t)i * 512 + tid + 256];
#pragma unroll
            for (int r = 0; r < 8; ++r) {
                const float h = hs[r][i];
                o0[r] = fmaf(h, w0, o0[r]);
                o1[r] = fmaf(h, w1, o1[r]);
            }
        }
    }
#pragma unroll
    for (int r = 0; r < 8; ++r) {
        feat2[(size_t)(row0 + r) * 512 + tid]       = o0[r];
        feat2[(size_t)(row0 + r) * 512 + tid + 256] = o1[r];
    }
}

// ---------------------------------------------------------------------------
// Kernel 3: linear interpolation nW=31 -> T=4096 (align_corners=False).
// Block handles 2 consecutive t of one b; 256 threads; float4 I/O.
// Output is never re-read -> nontemporal stores (native vector type).
// ---------------------------------------------------------------------------
__global__ __launch_bounds__(256) void k_interp(const float* __restrict__ feat2,
                                                float* __restrict__ out) {
    const int tid  = threadIdx.x;
    const int bt   = blockIdx.x * 2 + (tid >> 7);  // global (b*T + t)
    const int d4   = tid & 127;                    // float4 index within row
    const int t    = bt & (TT - 1);
    const int b    = bt >> 12;

    float pos = ((float)t + 0.5f) * (31.0f / 4096.0f) - 0.5f;
    pos = fminf(fmaxf(pos, 0.0f), 30.0f);
    const int   i0 = (int)pos;            // pos >= 0, trunc == floor
    const int   i1 = min(i0 + 1, 30);
    const float w  = pos - (float)i0;
    const float w0 = 1.0f - w;

    const f32x4* r0 = (const f32x4*)(feat2 + ((size_t)b * NW + i0) * DD);
    const f32x4* r1 = (const f32x4*)(feat2 + ((size_t)b * NW + i1) * DD);
    f32x4* o = (f32x4*)(out + (size_t)bt * DD);

    const f32x4 a  = r0[d4];
    const f32x4 cc = r1[d4];
    f32x4 res = a * w0 + cc * w;
    __builtin_nontemporal_store(res, &o[d4]);
}

// ---------------------------------------------------------------------------
extern "C" void kernel_launch(void* const* d_in, const int* in_sizes, int n_in,
                              void* d_out, int out_size, void* d_ws, size_t ws_size,
                              hipStream_t stream) {
    const float* x  = (const float*)d_in[0];
    const float* W1 = (const float*)d_in[1];
    const float* b1 = (const float*)d_in[2];
    const float* W2 = (const float*)d_in[3];
    const float* b2 = (const float*)d_in[4];
    float* out = (float*)d_out;

    float* feat  = (float*)d_ws;                 // NROWS*320 floats = 1.27 MB
    float* feat2 = feat + (size_t)NROWS * 320;   // NROWS*512 floats = 2.03 MB

    k_bandpower<<<NROWS, 512, 0, stream>>>(x, feat);
    k_mlp<<<NROWS / 8, 256, 0, stream>>>(feat, W1, b1, W2, b2, feat2);
    k_interp<<<(BB * TT) / 2, 256, 0, stream>>>(feat2, out);
}